// Round 5
// baseline (718.417 us; speedup 1.0000x reference)
//
#include <hip/hip_runtime.h>
#include <hip/hip_bf16.h>
#include <math.h>

#define BATCH   2
#define SEQ     2048
#define DM      2048
#define NH      16
#define QKR     64
#define QKN     128
#define KVL     512
#define VD      128
#define QKD     192     // QKN + QKR
#define KVA_LD  640     // padded row stride of kv_a (576 -> 640 for 128-tile GEMM)
#define RMS_EPS 1.1920928955078125e-07f

typedef __bf16 bf16x8 __attribute__((ext_vector_type(8)));
typedef __bf16 bf16x4 __attribute__((ext_vector_type(4)));
typedef float  f32x4  __attribute__((ext_vector_type(4)));

// ---- async global->LDS 16B copy (wave-uniform base + lane*16 dest semantics) ----
__device__ __forceinline__ void async16(const __bf16* g, __bf16* l)
{
    __builtin_amdgcn_global_load_lds(
        (__attribute__((address_space(1))) unsigned int*)g,
        (__attribute__((address_space(3))) unsigned int*)l,
        16, 0, 0);
}

// ---------------- fp32 [n] -> bf16 [n] ----------------
__global__ __launch_bounds__(256) void f32_to_bf16(const float* __restrict__ src,
                                                   __bf16* __restrict__ dst)
{
    int i = (blockIdx.x * 256 + threadIdx.x) * 4;
    float4 v = *reinterpret_cast<const float4*>(src + i);
    dst[i + 0] = (__bf16)v.x;
    dst[i + 1] = (__bf16)v.y;
    dst[i + 2] = (__bf16)v.z;
    dst[i + 3] = (__bf16)v.w;
}

// ---------------- W fp32 [K,N] -> W^T bf16 [Nout,K], zero-pad rows n>=N ----------------
__global__ __launch_bounds__(256) void transpose_w(const float* __restrict__ W,
                                                   __bf16* __restrict__ Wt,
                                                   int K, int N)
{
    __shared__ float t[64][65];
    const int n0 = blockIdx.x * 64, k0 = blockIdx.y * 64;
    const int tid = threadIdx.x;
    #pragma unroll
    for (int i = 0; i < 16; ++i) {
        int flat = i * 256 + tid;
        int kl = flat >> 6, nl = flat & 63;
        t[kl][nl] = (n0 + nl < N) ? W[(size_t)(k0 + kl) * N + n0 + nl] : 0.f;
    }
    __syncthreads();
    #pragma unroll
    for (int i = 0; i < 16; ++i) {
        int flat = i * 256 + tid;
        int nl = flat >> 6, kl = flat & 63;
        Wt[(size_t)(n0 + nl) * K + k0 + kl] = (__bf16)t[kl][nl];
    }
}

// ---------------- bf16 MFMA GEMM: C[M,N] = A[M,K] @ Bt[N,K]^T ----------------
template<typename OT>
__global__ __launch_bounds__(256) void gemm_bf16(const __bf16* __restrict__ A,
                                                 const __bf16* __restrict__ Bt,
                                                 OT* __restrict__ C,
                                                 int K, int lda, int ldb, int ldc)
{
    __shared__ __bf16 As[128 * 32];
    __shared__ __bf16 Bs[128 * 32];
    const int tid = threadIdx.x;
    const int lane = tid & 63, wave = tid >> 6;
    const int n = lane & 15, quad = lane >> 4;
    const int row0 = blockIdx.y * 128, col0 = blockIdx.x * 128;
    const int wm = (wave >> 1) * 64, wn = (wave & 1) * 64;

    f32x4 acc[4][4];
    #pragma unroll
    for (int mi = 0; mi < 4; ++mi)
        #pragma unroll
        for (int ni = 0; ni < 4; ++ni)
            #pragma unroll
            for (int r = 0; r < 4; ++r) acc[mi][ni][r] = 0.f;

    const __bf16* Ag0 = A  + (size_t)(row0 + (tid >> 2)) * lda + (tid & 3) * 8;
    const __bf16* Bg0 = Bt + (size_t)(col0 + (tid >> 2)) * ldb + (tid & 3) * 8;
    const __bf16* Ag1 = Ag0 + (size_t)64 * lda;
    const __bf16* Bg1 = Bg0 + (size_t)64 * ldb;
    __bf16* As0 = As + tid * 8;        __bf16* As1 = As + (tid + 256) * 8;
    __bf16* Bs0 = Bs + tid * 8;        __bf16* Bs1 = Bs + (tid + 256) * 8;

    for (int k0 = 0; k0 < K; k0 += 32) {
        __syncthreads();
        async16(Ag0 + k0, As0);
        async16(Ag1 + k0, As1);
        async16(Bg0 + k0, Bs0);
        async16(Bg1 + k0, Bs1);
        __syncthreads();

        bf16x8 af[4], bfr[4];
        #pragma unroll
        for (int mi = 0; mi < 4; ++mi)
            af[mi] = *reinterpret_cast<const bf16x8*>(&As[(wm + mi * 16 + n) * 32 + quad * 8]);
        #pragma unroll
        for (int ni = 0; ni < 4; ++ni)
            bfr[ni] = *reinterpret_cast<const bf16x8*>(&Bs[(wn + ni * 16 + n) * 32 + quad * 8]);
        #pragma unroll
        for (int mi = 0; mi < 4; ++mi)
            #pragma unroll
            for (int ni = 0; ni < 4; ++ni)
                acc[mi][ni] = __builtin_amdgcn_mfma_f32_16x16x32_bf16(af[mi], bfr[ni], acc[mi][ni], 0, 0, 0);
    }

    #pragma unroll
    for (int mi = 0; mi < 4; ++mi)
        #pragma unroll
        for (int r = 0; r < 4; ++r) {
            OT* cp = C + (size_t)(row0 + wm + mi * 16 + quad * 4 + r) * ldc + col0 + wn + n;
            #pragma unroll
            for (int ni = 0; ni < 4; ++ni)
                cp[ni * 16] = (OT)acc[mi][ni][r];
        }
}

// ---------------- RoPE on q (bf16, in-place), fp32 math ----------------
__global__ __launch_bounds__(256) void rope_q_kernel(__bf16* __restrict__ q)
{
    int idx = blockIdx.x * 256 + threadIdx.x;   // B*S*NH*32
    int i = idx & 31;
    int h = (idx >> 5) & 15;
    int s = (idx >> 9) & 2047;
    int b = idx >> 20;
    float t = (float)s * __expf(-(float)(2 * i) / 64.0f * 9.210340371976184f); // ln(10000)
    float c = __cosf(t), sn = __sinf(t);
    __bf16* p = q + ((size_t)(b * SEQ + s)) * (NH * QKD) + h * QKD + QKN + 2 * i;
    float x1 = (float)p[0], x2 = (float)p[1];
    p[0] = (__bf16)(x1 * c - x2 * sn);
    p[1] = (__bf16)(x2 * c + x1 * sn);
}

// ---------------- RoPE on k_rope: kv_a fp32 cols [512,576) -> bf16 krope [B,S,64] ----------------
__global__ __launch_bounds__(256) void rope_k_kernel(const float* __restrict__ kva,
                                                     __bf16* __restrict__ krope)
{
    int idx = blockIdx.x * 256 + threadIdx.x;   // B*S*32
    int i = idx & 31;
    int s = (idx >> 5) & 2047;
    int b = idx >> 16;
    float t = (float)s * __expf(-(float)(2 * i) / 64.0f * 9.210340371976184f);
    float c = __cosf(t), sn = __sinf(t);
    const float* p = kva + ((size_t)(b * SEQ + s)) * KVA_LD + KVL + 2 * i;
    float x1 = p[0], x2 = p[1];
    __bf16* o = krope + ((size_t)(b * SEQ + s)) * QKR + 2 * i;
    o[0] = (__bf16)(x1 * c - x2 * sn);
    o[1] = (__bf16)(x2 * c + x1 * sn);
}

// ---------------- RMSNorm c_kv (fp32 in, stride 640) -> bf16 out [4096,512] ----------------
__global__ __launch_bounds__(256) void rmsnorm_kernel(const float* __restrict__ kva,
                                                      const float* __restrict__ w,
                                                      __bf16* __restrict__ out)
{
    const int rid = blockIdx.x;
    const float* row = kva + (size_t)rid * KVA_LD;
    const int tid = threadIdx.x;
    float v[2];
    float ss = 0.f;
    #pragma unroll
    for (int j = 0; j < 2; ++j) {
        int d = tid + j * 256;
        v[j] = row[d];
        ss += v[j] * v[j];
    }
    #pragma unroll
    for (int off = 32; off > 0; off >>= 1) ss += __shfl_down(ss, off, 64);
    __shared__ float red[4];
    if ((tid & 63) == 0) red[tid >> 6] = ss;
    __syncthreads();
    float total = red[0] + red[1] + red[2] + red[3];
    float scale = 1.0f / sqrtf(total * (1.0f / KVL) + RMS_EPS);
    #pragma unroll
    for (int j = 0; j < 2; ++j) {
        int d = tid + j * 256;
        out[(size_t)rid * KVL + d] = (__bf16)(v[j] * scale * w[d]);
    }
}

// ---------------- build bf16 V^T : [B,H,128,S] from bf16 kv_b ----------------
__global__ __launch_bounds__(256) void build_vt(const __bf16* __restrict__ kvb,
                                                __bf16* __restrict__ Vt)
{
    __shared__ __bf16 tile[64][136];
    const int s0 = blockIdx.x * 64, h = blockIdx.y, b = blockIdx.z;
    const int t = threadIdx.x;
    #pragma unroll
    for (int i = 0; i < 4; ++i) {
        int flat = i * 256 + t;
        int sl = flat >> 4, c8 = flat & 15;
        bf16x8 v = *reinterpret_cast<const bf16x8*>(
            &kvb[((size_t)(b * SEQ + s0 + sl)) * (NH * 256) + h * 256 + 128 + c8 * 8]);
        *reinterpret_cast<bf16x8*>(&tile[sl][c8 * 8]) = v;
    }
    __syncthreads();
    #pragma unroll
    for (int j = 0; j < 32; ++j) {
        int flat = j * 256 + t;
        int d = flat >> 6, sl = flat & 63;
        Vt[((size_t)((b * NH + h) * VD + d)) * SEQ + s0 + sl] = tile[sl][d];
    }
}

// ---------------- MFMA flash attention, paired q-strips, 2-way split-K ----------------
// Block = (pair p, half hf): strips p and 31-p, k-tiles {hf, hf+2, ...}.
// Emits unnormalized partial O (bf16) + (m,l) per row; combine kernel merges halves.
// Grid 1024 blocks, LDS 53,248 B -> 3 blocks/CU resident. XCD-swizzled (b,h).
#define LKS 200   // 192 + 8 pad
#define LVS 72    // 64 + 8
#define LPS 72
#define OPHALF 8388608   // bf16 elems per half: 4096*16*128
__global__ __launch_bounds__(256, 3) void attn_mfma(const __bf16* __restrict__ qb,
                                                    const __bf16* __restrict__ kvb,
                                                    const __bf16* __restrict__ krope,
                                                    const __bf16* __restrict__ Vt,
                                                    __bf16* __restrict__ Op,
                                                    float* __restrict__ Ml)
{
    __shared__ __bf16 Ks[64 * LKS];        // 25600 B
    __shared__ __bf16 Vs[128 * LVS];       // 18432 B
    __shared__ __bf16 Ps[4 * 16 * LPS];    //  9216 B   (total 53248 B)
    const int tid = threadIdx.x;
    const int wave = tid >> 6, lane = tid & 63;
    const int n = lane & 15, quad = lane >> 4;

    // XCD swizzle: all 32 blocks of one (b,h) on one XCD (j%8 heuristic)
    const int j = blockIdx.x + 32 * (blockIdx.y + 16 * blockIdx.z);
    const int xcd = j & 7, loc = j >> 3;
    const int hb = xcd * 4 + (loc & 3);
    const int slot = loc >> 2;                 // 0..31
    const int pair = slot >> 1, hf = slot & 1;
    const int h = hb & 15, b = hb >> 4;
    const int bh = b * NH + h;
    const float scale = 0.07216878364870323f;   // 1/sqrt(192)
    int qs[2];
    qs[0] = pair; qs[1] = 31 - pair;
    const int ntmax = 32 - pair;               // tiles needed by the long strip

    // Q fragments for both strips (A-layout: m=n, k=quad*8+j)
    bf16x8 qfrag[2][6];
    #pragma unroll
    for (int s = 0; s < 2; ++s) {
        const int qrow = qs[s] * 64 + wave * 16 + n;
        const __bf16* qp = qb + ((size_t)(b * SEQ + qrow)) * (NH * QKD) + h * QKD + quad * 8;
        #pragma unroll
        for (int c = 0; c < 6; ++c)
            qfrag[s][c] = *reinterpret_cast<const bf16x8*>(qp + c * 32);
    }

    f32x4 Oa[2][8];
    float m_i[2][4], l_i[2][4];
    #pragma unroll
    for (int s = 0; s < 2; ++s) {
        #pragma unroll
        for (int i = 0; i < 8; ++i)
            #pragma unroll
            for (int r = 0; r < 4; ++r) Oa[s][i][r] = 0.f;
        #pragma unroll
        for (int r = 0; r < 4; ++r) { m_i[s][r] = -1e30f; l_i[s][r] = 0.f; }
    }

    // per-thread staging coordinates
    int kkey[6], kc8[6];
    #pragma unroll
    for (int i = 0; i < 6; ++i) {
        int flat = i * 256 + tid;
        kkey[i] = flat / 24; kc8[i] = flat % 24;
    }
    const int vd = tid >> 3, vc8 = tid & 7;

    const __bf16* Vg = Vt + (size_t)bh * VD * SEQ;

    bf16x8 kpre[6], vpre[4];
    // prefetch first tile (kt = hf)
    {
        const int k0 = hf * 64;
        #pragma unroll
        for (int i = 0; i < 6; ++i) {
            const __bf16* src = (kc8[i] < 16)
                ? kvb + ((size_t)(b * SEQ + k0 + kkey[i])) * (NH * 256) + h * 256 + kc8[i] * 8
                : krope + ((size_t)(b * SEQ + k0 + kkey[i])) * QKR + (kc8[i] - 16) * 8;
            kpre[i] = *reinterpret_cast<const bf16x8*>(src);
        }
        #pragma unroll
        for (int i = 0; i < 4; ++i)
            vpre[i] = *reinterpret_cast<const bf16x8*>(Vg + (size_t)(vd + i * 32) * SEQ + k0 + vc8 * 8);
    }

    for (int kt = hf; kt < ntmax; kt += 2) {
        __syncthreads();   // previous iteration's compute done; Ks/Vs safe to overwrite
        #pragma unroll
        for (int i = 0; i < 6; ++i)
            *reinterpret_cast<bf16x8*>(&Ks[kkey[i] * LKS + kc8[i] * 8]) = kpre[i];
        #pragma unroll
        for (int i = 0; i < 4; ++i)
            *reinterpret_cast<bf16x8*>(&Vs[(vd + i * 32) * LVS + vc8 * 8]) = vpre[i];
        __syncthreads();

        // prefetch next tile (kt+2) into registers (overlaps compute)
        if (kt + 2 < ntmax) {
            const int k0n = (kt + 2) * 64;
            #pragma unroll
            for (int i = 0; i < 6; ++i) {
                const __bf16* src = (kc8[i] < 16)
                    ? kvb + ((size_t)(b * SEQ + k0n + kkey[i])) * (NH * 256) + h * 256 + kc8[i] * 8
                    : krope + ((size_t)(b * SEQ + k0n + kkey[i])) * QKR + (kc8[i] - 16) * 8;
                kpre[i] = *reinterpret_cast<const bf16x8*>(src);
            }
            #pragma unroll
            for (int i = 0; i < 4; ++i)
                vpre[i] = *reinterpret_cast<const bf16x8*>(Vg + (size_t)(vd + i * 32) * SEQ + k0n + vc8 * 8);
        }

        const int k0 = kt * 64;
        #pragma unroll
        for (int s = 0; s < 2; ++s) {
            if (kt > qs[s]) continue;      // strip 0 finished past its diagonal

            // scores: S[16q x 64k], 4 key-subtiles x 6 d-chunks
            f32x4 sacc[4];
            #pragma unroll
            for (int t = 0; t < 4; ++t) {
                f32x4 a;
                #pragma unroll
                for (int r = 0; r < 4; ++r) a[r] = 0.f;
                #pragma unroll
                for (int c = 0; c < 6; ++c) {
                    bf16x8 kf = *reinterpret_cast<const bf16x8*>(&Ks[(t * 16 + n) * LKS + c * 32 + quad * 8]);
                    a = __builtin_amdgcn_mfma_f32_16x16x32_bf16(qfrag[s][c], kf, a, 0, 0, 0);
                }
                sacc[t] = a;
            }

            const int qg = qs[s] * 64 + wave * 16 + quad * 4;
            const bool diag = (kt == qs[s]);
            float mloc[4];
            #pragma unroll
            for (int r = 0; r < 4; ++r) mloc[r] = -1e30f;
            #pragma unroll
            for (int t = 0; t < 4; ++t) {
                int key = k0 + t * 16 + n;
                #pragma unroll
                for (int r = 0; r < 4; ++r) {
                    float sv = sacc[t][r] * scale;
                    if (diag) sv = (key <= qg + r) ? sv : -1e30f;
                    sacc[t][r] = sv;
                    mloc[r] = fmaxf(mloc[r], sv);
                }
            }
            #pragma unroll
            for (int off = 1; off < 16; off <<= 1)
                #pragma unroll
                for (int r = 0; r < 4; ++r)
                    mloc[r] = fmaxf(mloc[r], __shfl_xor(mloc[r], off, 64));
            float alpha[4], sum[4];
            #pragma unroll
            for (int r = 0; r < 4; ++r) {
                float mn = fmaxf(m_i[s][r], mloc[r]);
                alpha[r] = __expf(m_i[s][r] - mn);
                m_i[s][r] = mn;
                sum[r] = 0.f;
            }
            #pragma unroll
            for (int t = 0; t < 4; ++t)
                #pragma unroll
                for (int r = 0; r < 4; ++r) {
                    float p = __expf(sacc[t][r] - m_i[s][r]);
                    sum[r] += p;
                    Ps[wave * 16 * LPS + (quad * 4 + r) * LPS + t * 16 + n] = (__bf16)p;
                }
            #pragma unroll
            for (int off = 1; off < 16; off <<= 1)
                #pragma unroll
                for (int r = 0; r < 4; ++r)
                    sum[r] += __shfl_xor(sum[r], off, 64);
            #pragma unroll
            for (int r = 0; r < 4; ++r) l_i[s][r] = l_i[s][r] * alpha[r] + sum[r];
            #pragma unroll
            for (int i = 0; i < 8; ++i)
                #pragma unroll
                for (int r = 0; r < 4; ++r) Oa[s][i][r] *= alpha[r];

            // drain P writes (per-wave region; in-wave ordering only)
            __asm__ volatile("s_waitcnt lgkmcnt(0)" ::: "memory");

            // PV: O[16q x 128vd] += P[16x64] * V[64x128]
            #pragma unroll
            for (int kc = 0; kc < 2; ++kc) {
                bf16x8 pf = *reinterpret_cast<const bf16x8*>(&Ps[wave * 16 * LPS + n * LPS + kc * 32 + quad * 8]);
                #pragma unroll
                for (int vt = 0; vt < 8; ++vt) {
                    bf16x8 vf = *reinterpret_cast<const bf16x8*>(&Vs[(vt * 16 + n) * LVS + kc * 32 + quad * 8]);
                    Oa[s][vt] = __builtin_amdgcn_mfma_f32_16x16x32_bf16(pf, vf, Oa[s][vt], 0, 0, 0);
                }
            }
        }
    }

    // epilogue: unnormalized partial O + (m,l)
    #pragma unroll
    for (int s = 0; s < 2; ++s)
        #pragma unroll
        for (int r = 0; r < 4; ++r) {
            int row = qs[s] * 64 + wave * 16 + quad * 4 + r;
            __bf16* op = Op + (size_t)hf * OPHALF + ((size_t)(b * SEQ + row) * NH + h) * VD;
            #pragma unroll
            for (int vt = 0; vt < 8; ++vt)
                op[vt * 16 + n] = (__bf16)Oa[s][vt][r];
            if (n == 0) {
                float* ml = Ml + (((size_t)hf * 4096 + b * SEQ + row) * NH + h) * 2;
                ml[0] = m_i[s][r];
                ml[1] = l_i[s][r];
            }
        }
}

// ---------------- combine the two split-K halves ----------------
__global__ __launch_bounds__(256) void attn_combine(const __bf16* __restrict__ Op,
                                                    const float* __restrict__ Ml,
                                                    __bf16* __restrict__ ob)
{
    int idx = blockIdx.x * 256 + threadIdx.x;    // B*S*NH*32 threads, 4 dims each
    int c4 = idx & 31;
    int h  = (idx >> 5) & 15;
    int row = idx >> 9;                          // b*SEQ + s
    const float* ml0 = Ml + ((size_t)row * NH + h) * 2;
    const float* ml1 = Ml + (((size_t)4096 + row) * NH + h) * 2;
    float m0 = ml0[0], l0 = ml0[1], m1 = ml1[0], l1 = ml1[1];
    float m = fmaxf(m0, m1);
    float w0 = __expf(m0 - m), w1 = __expf(m1 - m);
    float inv = 1.0f / (w0 * l0 + w1 * l1);
    size_t off = ((size_t)row * NH + h) * VD + c4 * 4;
    bf16x4 o0 = *reinterpret_cast<const bf16x4*>(Op + off);
    bf16x4 o1 = *reinterpret_cast<const bf16x4*>(Op + OPHALF + off);
    bf16x4 o;
    #pragma unroll
    for (int i = 0; i < 4; ++i)
        o[i] = (__bf16)((w0 * (float)o0[i] + w1 * (float)o1[i]) * inv);
    *reinterpret_cast<bf16x4*>(ob + off) = o;
}

extern "C" void kernel_launch(void* const* d_in, const int* in_sizes, int n_in,
                              void* d_out, int out_size, void* d_ws, size_t ws_size,
                              hipStream_t stream)
{
    const float* x         = (const float*)d_in[0];
    const float* Wq        = (const float*)d_in[1];
    const float* Wkv_a     = (const float*)d_in[2];
    const float* kv_norm_w = (const float*)d_in[3];
    const float* Wkv_b     = (const float*)d_in[4];
    const float* Wo        = (const float*)d_in[5];
    float* out = (float*)d_out;

    // workspace layout (f32-unit offsets); total 38,273,024 f = 153.1 MB
    float* ws = (float*)d_ws;
    __bf16* q_bf   = (__bf16*)ws;                              // [0, 6291456)
    float*  kv_a   = ws + 6291456;                             // [6291456, 8912896)
    __bf16* kv_b   = (__bf16*)(ws + 8912896);                  // [8912896, 17301504)
    __bf16* xb     = (__bf16*)(ws + 17301504);                 // [17301504, 21495808)
    __bf16* Vt     = (__bf16*)(ws + 17301504);                 // alias: xb dead before build_vt
    float*  r4     = ws + 21495808;                            // weights then attn_o (alias)
    __bf16* Wq_t   = (__bf16*)r4;                              // 3,145,728 f
    __bf16* Wkva_t = (__bf16*)(ws + 24641536);                 //   655,360 f
    __bf16* Wkvb_t = (__bf16*)(ws + 25296896);                 // 1,048,576 f -> ends 26345472
    __bf16* attn_o = (__bf16*)r4;                              // 4,194,304 f (weights dead)
    __bf16* Wo_t   = (__bf16*)(ws + 26345472);                 // 2,097,152 f
    __bf16* c_kv_n = (__bf16*)(ws + 28442624);                 // 1,048,576 f
    __bf16* krope  = (__bf16*)(ws + 29491200);                 //   131,072 f
    float*  Ml     = ws + 29622272;                            //   262,144 f
    __bf16* Op     = (__bf16*)(ws + 29884416);                 // 8,388,608 f (2 halves bf16)

    const int M = BATCH * SEQ;   // 4096
    dim3 blk(256);

    f32_to_bf16<<<(M * DM) / 1024, blk, 0, stream>>>(x, xb);
    transpose_w<<<dim3(3072 / 64, 2048 / 64), blk, 0, stream>>>(Wq, Wq_t, DM, NH * QKD);
    transpose_w<<<dim3(640 / 64, 2048 / 64), blk, 0, stream>>>(Wkv_a, Wkva_t, DM, KVL + QKR);
    transpose_w<<<dim3(4096 / 64, 512 / 64), blk, 0, stream>>>(Wkv_b, Wkvb_t, KVL, NH * 256);
    transpose_w<<<dim3(2048 / 64, 2048 / 64), blk, 0, stream>>>(Wo, Wo_t, NH * VD, DM);

    gemm_bf16<__bf16><<<dim3(3072 / 128, M / 128), blk, 0, stream>>>(xb, Wq_t, q_bf, DM, DM, DM, NH * QKD);
    gemm_bf16<float><<<dim3(640 / 128, M / 128), blk, 0, stream>>>(xb, Wkva_t, kv_a, DM, DM, DM, KVA_LD);

    rope_q_kernel<<<(BATCH * SEQ * NH * 32) / 256, blk, 0, stream>>>(q_bf);
    rope_k_kernel<<<(BATCH * SEQ * 32) / 256, blk, 0, stream>>>(kv_a, krope);
    rmsnorm_kernel<<<M, blk, 0, stream>>>(kv_a, kv_norm_w, c_kv_n);

    gemm_bf16<__bf16><<<dim3(4096 / 128, M / 128), blk, 0, stream>>>(c_kv_n, Wkvb_t, kv_b, KVL, KVL, KVL, NH * 256);

    build_vt<<<dim3(SEQ / 64, NH, BATCH), blk, 0, stream>>>(kv_b, Vt);

    attn_mfma<<<dim3(32, NH, BATCH), blk, 0, stream>>>(q_bf, kv_b, krope, Vt, Op, Ml);
    attn_combine<<<(M * NH * 32) / 256, blk, 0, stream>>>(Op, Ml, attn_o);

    gemm_bf16<float><<<dim3(2048 / 128, M / 128), blk, 0, stream>>>(attn_o, Wo_t, out, NH * VD, NH * VD, NH * VD, DM);
}